// Round 1
// baseline (295.678 us; speedup 1.0000x reference)
//
#include <hip/hip_runtime.h>
#include <hip/hip_bf16.h>
#include <math.h>

#define Nn 8192
#define Mm 8192
#define DIM 128
#define EPS_F 0.001
#define GPU_ITERS 6

typedef __attribute__((ext_vector_type(8))) short bf16x8;
typedef __attribute__((ext_vector_type(4))) float f32x4;
typedef __attribute__((ext_vector_type(8))) unsigned short u16x8;
typedef __attribute__((ext_vector_type(4))) unsigned short u16x4;
typedef __attribute__((ext_vector_type(4))) float f4;

struct Scal {
  unsigned int wmax_bits;
  float c;
  int done_iter;
  int final_parity;
  double S_u;
};

__device__ __forceinline__ float bf2f(unsigned short u) {
  unsigned int x = ((unsigned int)u) << 16;
  return __uint_as_float(x);
}

// ---- prep: bf16 convert + row squared-norms. 1 wave per row (DIM=128 = 64 lanes x 2) ----
__global__ __launch_bounds__(256) void prep_norms(const float* __restrict__ X,
    unsigned short* __restrict__ Xb, float* __restrict__ X2) {
  int gid = blockIdx.x * blockDim.x + threadIdx.x;
  int row = gid >> 6;
  int lane = gid & 63;
  const float* rp = X + (size_t)row * DIM + lane * 2;
  float a = rp[0], b = rp[1];
  __hip_bfloat16 ha = __float2bfloat16(a), hb = __float2bfloat16(b);
  unsigned short sa = *(unsigned short*)&ha, sb = *(unsigned short*)&hb;
  unsigned int packed = (unsigned int)sa | ((unsigned int)sb << 16);
  *(unsigned int*)(Xb + (size_t)row * DIM + lane * 2) = packed;
  float s = a * a + b * b;
  for (int off = 32; off; off >>= 1) s += __shfl_down(s, off, 64);
  if (lane == 0) X2[row] = s;
}

// ---- init state each call (ws is poisoned 0xAA, never re-poisoned between replays) ----
__global__ void init_state(float* v, float* u_old, double* svpart, Scal* sc) {
  int t = blockIdx.x * blockDim.x + threadIdx.x; // 32*256 = 8192
  v[t] = 1.0f / (float)Mm;
  u_old[t] = 1.0f / (float)Nn;
  if (t < 64) svpart[t] = (t == 0) ? 1.0 : 0.0; // sum(v0) = 1.0 exactly (2^-13 each)
  if (t == 0) { sc->wmax_bits = 0u; sc->done_iter = 1 << 29; sc->final_parity = 0; }
}

// ---- W build: 128x128 tile per block, 4 waves of 64x64, mfma 16x16x32 bf16, K=128 ----
__global__ __launch_bounds__(256) void build_w(const unsigned short* __restrict__ xb,
    const unsigned short* __restrict__ yb, const float* __restrict__ x2,
    const float* __restrict__ y2, unsigned short* __restrict__ Wb, Scal* sc) {
  int bid = blockIdx.x;              // 64 x 64 tiles
  int bi = bid >> 6, bj = bid & 63;
  int wv = threadIdx.x >> 6, lane = threadIdx.x & 63;
  int row0 = bi * 128 + (wv >> 1) * 64;
  int col0 = bj * 128 + (wv & 1) * 64;
  int fr = lane & 15, fg = lane >> 4;
  f32x4 acc[4][4];
  #pragma unroll
  for (int m = 0; m < 4; ++m)
    #pragma unroll
    for (int n = 0; n < 4; ++n) acc[m][n] = (f32x4){0.f, 0.f, 0.f, 0.f};
  #pragma unroll
  for (int kk = 0; kk < 4; ++kk) {
    int k0 = kk * 32 + fg * 8;
    bf16x8 a[4], b[4];
    #pragma unroll
    for (int m = 0; m < 4; ++m)
      a[m] = *(const bf16x8*)(xb + (size_t)(row0 + m * 16 + fr) * DIM + k0);
    #pragma unroll
    for (int n = 0; n < 4; ++n)
      b[n] = *(const bf16x8*)(yb + (size_t)(col0 + n * 16 + fr) * DIM + k0);
    #pragma unroll
    for (int m = 0; m < 4; ++m)
      #pragma unroll
      for (int n = 0; n < 4; ++n)
        acc[m][n] = __builtin_amdgcn_mfma_f32_16x16x32_bf16(a[m], b[n], acc[m][n], 0, 0, 0);
  }
  float wm = 0.f;
  #pragma unroll
  for (int m = 0; m < 4; ++m) {
    #pragma unroll
    for (int r = 0; r < 4; ++r) {
      int i = row0 + m * 16 + fg * 4 + r;
      float xi = x2[i];
      #pragma unroll
      for (int n = 0; n < 4; ++n) {
        int j = col0 + n * 16 + fr;
        float d2 = xi + y2[j] - 2.0f * acc[m][n][r];
        float w = sqrtf(fmaxf(d2, 0.f));
        wm = fmaxf(wm, w);
        __hip_bfloat16 h = __float2bfloat16(w);
        Wb[(size_t)i * Mm + j] = *(unsigned short*)&h;
      }
    }
  }
  for (int off = 32; off; off >>= 1) wm = fmaxf(wm, __shfl_down(wm, off, 64));
  __shared__ float smax[4];
  if (lane == 0) smax[wv] = wm;
  __syncthreads();
  if (threadIdx.x == 0) {
    float m4 = fmaxf(fmaxf(smax[0], smax[1]), fmaxf(smax[2], smax[3]));
    atomicMax(&sc->wmax_bits, __float_as_uint(m4)); // positive floats: uint order == float order
  }
}

__global__ void compute_c(Scal* sc) {
  float wmax = __uint_as_float(sc->wmax_bits);
  sc->c = (float)(EPS_F) / (128.0f * wmax);
}

// ---- row matvec: u_new_i = 1 / (S_v - c * sum_j W_ij v_j), fp64 accumulate ----
__global__ __launch_bounds__(256) void matvec_u(const unsigned short* __restrict__ Wb,
    const float* __restrict__ v, const double* __restrict__ svpart,
    float* __restrict__ unew, const Scal* __restrict__ sc, int it) {
  if (it > sc->done_iter) return; // frozen after convergence (ref 'done' semantics)
  double S_v = 0.0;
  #pragma unroll
  for (int k = 0; k < 64; ++k) S_v += svpart[k];
  int gid = blockIdx.x * blockDim.x + threadIdx.x;
  int row = gid >> 6, lane = gid & 63;
  const unsigned short* wr = Wb + (size_t)row * Mm;
  double acc0 = 0.0, acc1 = 0.0;
  for (int p = 0; p < 16; ++p) {
    int j0 = p * 512 + lane * 8;
    u16x8 w8 = *(const u16x8*)(wr + j0);
    f4 v0 = *(const f4*)(v + j0);
    f4 v1 = *(const f4*)(v + j0 + 4);
    #pragma unroll
    for (int q = 0; q < 4; ++q) {
      acc0 += (double)bf2f(w8[q]) * (double)v0[q];
      acc1 += (double)bf2f(w8[q + 4]) * (double)v1[q];
    }
  }
  double a = acc0 + acc1;
  for (int off = 32; off; off >>= 1) a += __shfl_down(a, off, 64);
  if (lane == 0) unew[row] = (float)(1.0 / (S_v - (double)sc->c * a));
}

// ---- S_u, delta, convergence decision (1 block; deterministic fixed-order sums) ----
__global__ __launch_bounds__(256) void reduce_u(const float* __restrict__ unew,
    const float* __restrict__ uold, Scal* sc, int it) {
  if (it > sc->done_iter) return;
  double su = 0.0, dd = 0.0;
  for (int i = threadIdx.x; i < Nn; i += 256) {
    float a = unew[i], b = uold[i];
    su += (double)a;
    dd += fabs((double)a - (double)b);
  }
  __shared__ double s1[256], s2[256];
  s1[threadIdx.x] = su; s2[threadIdx.x] = dd;
  __syncthreads();
  for (int off = 128; off; off >>= 1) {
    if (threadIdx.x < off) { s1[threadIdx.x] += s1[threadIdx.x + off]; s2[threadIdx.x] += s2[threadIdx.x + off]; }
    __syncthreads();
  }
  if (threadIdx.x == 0) {
    sc->S_u = s1[0];
    sc->final_parity = it & 1;
    if (s2[0] < (double)EPS_F) sc->done_iter = it; // this iter still finishes its v-update
  }
}

// ---- transposed matvec: partials of sum_i W_ij u_i ; 64 col-stripes x 16 row-chunks ----
__global__ __launch_bounds__(256) void matvec_t(const unsigned short* __restrict__ Wb,
    const float* __restrict__ u, double* __restrict__ tpart,
    const Scal* __restrict__ sc, int it) {
  if (it > sc->done_iter) return;
  int bid = blockIdx.x;
  int cs = bid & 63, rc = bid >> 6;
  int c0 = cs * 128, r0 = rc * 512;
  int cg = threadIdx.x & 31, ro = threadIdx.x >> 5;
  double a0 = 0, a1 = 0, a2 = 0, a3 = 0;
  for (int i = 0; i < 64; ++i) {
    int r = r0 + i * 8 + ro;
    const unsigned short* wp = Wb + (size_t)r * Mm + c0 + cg * 4;
    u16x4 w4 = *(const u16x4*)wp;
    double ud = (double)u[r];
    a0 += (double)bf2f(w4[0]) * ud;
    a1 += (double)bf2f(w4[1]) * ud;
    a2 += (double)bf2f(w4[2]) * ud;
    a3 += (double)bf2f(w4[3]) * ud;
  }
  __shared__ double sm[8][32][4]; // 8 KiB
  sm[ro][cg][0] = a0; sm[ro][cg][1] = a1; sm[ro][cg][2] = a2; sm[ro][cg][3] = a3;
  __syncthreads();
  if (threadIdx.x < 128) {
    int col = threadIdx.x;
    double s = 0;
    #pragma unroll
    for (int k = 0; k < 8; ++k) s += sm[k][col >> 2][col & 3];
    tpart[(size_t)rc * Mm + c0 + col] = s;
  }
}

// ---- v_new from partials + S_v block partials ----
__global__ __launch_bounds__(128) void reduce_v(const double* __restrict__ tpart,
    float* __restrict__ v, double* __restrict__ svpart,
    const Scal* __restrict__ sc, int it) {
  if (it > sc->done_iter) return;
  int col = blockIdx.x * 128 + threadIdx.x;
  double s = 0;
  #pragma unroll
  for (int k = 0; k < 16; ++k) s += tpart[(size_t)k * Mm + col];
  double vnew = 1.0 / (sc->S_u - (double)sc->c * s);
  float vf = (float)vnew;
  v[col] = vf;
  __shared__ double sd[128];
  sd[threadIdx.x] = (double)vf;
  __syncthreads();
  for (int off = 64; off; off >>= 1) {
    if (threadIdx.x < off) sd[threadIdx.x] += sd[threadIdx.x + off];
    __syncthreads();
  }
  if (threadIdx.x == 0) svpart[blockIdx.x] = sd[0];
}

// ---- final: divpart_i = u_i * (Kx v)_i ----
__global__ __launch_bounds__(256) void matvec_div(const unsigned short* __restrict__ Wb,
    const float* __restrict__ v, const float* __restrict__ u0, const float* __restrict__ u1,
    const double* __restrict__ svpart, double* __restrict__ divpart,
    const Scal* __restrict__ sc) {
  double S_v = 0.0;
  #pragma unroll
  for (int k = 0; k < 64; ++k) S_v += svpart[k];
  const float* u = sc->final_parity ? u1 : u0;
  int gid = blockIdx.x * blockDim.x + threadIdx.x;
  int row = gid >> 6, lane = gid & 63;
  const unsigned short* wr = Wb + (size_t)row * Mm;
  double acc0 = 0.0, acc1 = 0.0;
  for (int p = 0; p < 16; ++p) {
    int j0 = p * 512 + lane * 8;
    u16x8 w8 = *(const u16x8*)(wr + j0);
    f4 v0 = *(const f4*)(v + j0);
    f4 v1 = *(const f4*)(v + j0 + 4);
    #pragma unroll
    for (int q = 0; q < 4; ++q) {
      acc0 += (double)bf2f(w8[q]) * (double)v0[q];
      acc1 += (double)bf2f(w8[q + 4]) * (double)v1[q];
    }
  }
  double a = acc0 + acc1;
  for (int off = 32; off; off >>= 1) a += __shfl_down(a, off, 64);
  if (lane == 0) divpart[row] = (double)u[row] * (S_v - (double)sc->c * a);
}

__global__ __launch_bounds__(256) void finalize(const double* __restrict__ divpart,
                                                float* __restrict__ out) {
  double s = 0;
  for (int i = threadIdx.x; i < Nn; i += 256) s += divpart[i];
  __shared__ double sd[256];
  sd[threadIdx.x] = s;
  __syncthreads();
  for (int off = 128; off; off >>= 1) {
    if (threadIdx.x < off) sd[threadIdx.x] += sd[threadIdx.x + off];
    __syncthreads();
  }
  if (threadIdx.x == 0) out[0] = (float)(sd[0] / (double)Nn);
}

extern "C" void kernel_launch(void* const* d_in, const int* in_sizes, int n_in,
                              void* d_out, int out_size, void* d_ws, size_t ws_size,
                              hipStream_t stream) {
  const float* x = (const float*)d_in[0];
  const float* y = (const float*)d_in[1];
  char* ws = (char*)d_ws;
  size_t off = 0;
  unsigned short* Wb = (unsigned short*)(ws + off); off += (size_t)Nn * Mm * 2;   // 128 MiB
  unsigned short* xb = (unsigned short*)(ws + off); off += (size_t)Nn * DIM * 2;  // 2 MiB
  unsigned short* yb = (unsigned short*)(ws + off); off += (size_t)Mm * DIM * 2;  // 2 MiB
  float* x2 = (float*)(ws + off); off += (size_t)Nn * 4;
  float* y2 = (float*)(ws + off); off += (size_t)Mm * 4;
  float* u0 = (float*)(ws + off); off += (size_t)Nn * 4;
  float* u1 = (float*)(ws + off); off += (size_t)Nn * 4;
  float* v  = (float*)(ws + off); off += (size_t)Mm * 4;
  double* tpart   = (double*)(ws + off); off += 16 * (size_t)Mm * 8;              // 1 MiB
  double* svpart  = (double*)(ws + off); off += 64 * 8;
  double* divpart = (double*)(ws + off); off += (size_t)Nn * 8;
  Scal* sc = (Scal*)(ws + off); off += sizeof(Scal);
  // total ~139.7 MB — assumes ws_size covers it

  prep_norms<<<2048, 256, 0, stream>>>(x, xb, x2);
  prep_norms<<<2048, 256, 0, stream>>>(y, yb, y2);
  init_state<<<32, 256, 0, stream>>>(v, u1, svpart, sc);
  build_w<<<4096, 256, 0, stream>>>(xb, yb, x2, y2, Wb, sc);
  compute_c<<<1, 1, 0, stream>>>(sc);

  float* ub[2] = {u0, u1};
  for (int it = 0; it < GPU_ITERS; ++it) {
    matvec_u<<<2048, 256, 0, stream>>>(Wb, v, svpart, ub[it & 1], sc, it);
    reduce_u<<<1, 256, 0, stream>>>(ub[it & 1], ub[(it & 1) ^ 1], sc, it);
    matvec_t<<<1024, 256, 0, stream>>>(Wb, ub[it & 1], tpart, sc, it);
    reduce_v<<<64, 128, 0, stream>>>(tpart, v, svpart, sc, it);
  }
  matvec_div<<<2048, 256, 0, stream>>>(Wb, v, u0, u1, svpart, divpart, sc);
  finalize<<<1, 256, 0, stream>>>(divpart, (float*)d_out);
}

// Round 2
// 125.808 us; speedup vs baseline: 2.3502x; 2.3502x over previous
//
#include <hip/hip_runtime.h>
#include <hip/hip_bf16.h>
#include <math.h>

#define Nn 8192
#define Mm 8192
#define DIM 128
#define EPS 0.001

typedef __attribute__((ext_vector_type(8))) short bf16x8;
typedef __attribute__((ext_vector_type(4))) float f32x4;

// ---- prep: bf16 convert + row squared-norms for BOTH x and y in one launch ----
// 4096 blocks x 256: first 2^19 threads -> x (8192 rows x 64 lanes), rest -> y
__global__ __launch_bounds__(256) void prep2(const float* __restrict__ X,
    const float* __restrict__ Y, unsigned short* __restrict__ Xb,
    unsigned short* __restrict__ Yb, float* __restrict__ X2, float* __restrict__ Y2) {
  int gid = blockIdx.x * blockDim.x + threadIdx.x;
  int half = gid >> 19;
  int g = gid & ((1 << 19) - 1);
  int row = g >> 6, lane = g & 63;
  const float* src = half ? Y : X;
  unsigned short* dst = half ? Yb : Xb;
  float* dn = half ? Y2 : X2;
  const float* rp = src + (size_t)row * DIM + lane * 2;
  float a = rp[0], b = rp[1];
  __hip_bfloat16 ha = __float2bfloat16(a), hb = __float2bfloat16(b);
  unsigned short sa = *(unsigned short*)&ha, sb = *(unsigned short*)&hb;
  *(unsigned int*)(dst + (size_t)row * DIM + lane * 2) =
      (unsigned int)sa | ((unsigned int)sb << 16);
  float s = a * a + b * b;
  for (int off = 32; off; off >>= 1) s += __shfl_down(s, off, 64);
  if (lane == 0) dn[row] = s;
}

// ws is poisoned 0xAA (a huge uint) once and never re-poisoned: reset max every call
__global__ void init_sc(unsigned int* wmax_bits) { *wmax_bits = 0u; }

// ---- fused GEMM + W-statistics: per 128x128 tile compute w=sqrt(x2+y2-2g) in
// registers; reduce to row-partials, col-partials, tile max. W is never stored. ----
__global__ __launch_bounds__(256) void fused_stats(const unsigned short* __restrict__ xb,
    const unsigned short* __restrict__ yb, const float* __restrict__ x2,
    const float* __restrict__ y2, float* __restrict__ Rpart, float* __restrict__ Cpart,
    unsigned int* __restrict__ wmax_bits) {
  int bid = blockIdx.x;              // 64 x 64 tiles of 128x128
  int bi = bid >> 6, bj = bid & 63;
  int wv = threadIdx.x >> 6, lane = threadIdx.x & 63;
  int rh = wv >> 1, ch = wv & 1;     // row half / col half of this wave's 64x64
  int row0 = bi * 128 + rh * 64;
  int col0 = bj * 128 + ch * 64;
  int fr = lane & 15, fg = lane >> 4;

  f32x4 acc[4][4];
  #pragma unroll
  for (int m = 0; m < 4; ++m)
    #pragma unroll
    for (int n = 0; n < 4; ++n) acc[m][n] = (f32x4){0.f, 0.f, 0.f, 0.f};
  #pragma unroll
  for (int kk = 0; kk < 4; ++kk) {
    int k0 = kk * 32 + fg * 8;
    bf16x8 a[4], b[4];
    #pragma unroll
    for (int m = 0; m < 4; ++m)
      a[m] = *(const bf16x8*)(xb + (size_t)(row0 + m * 16 + fr) * DIM + k0);
    #pragma unroll
    for (int n = 0; n < 4; ++n)
      b[n] = *(const bf16x8*)(yb + (size_t)(col0 + n * 16 + fr) * DIM + k0);
    #pragma unroll
    for (int m = 0; m < 4; ++m)
      #pragma unroll
      for (int n = 0; n < 4; ++n)
        acc[m][n] = __builtin_amdgcn_mfma_f32_16x16x32_bf16(a[m], b[n], acc[m][n], 0, 0, 0);
  }

  // epilogue: w[m][n][r] for row i=row0+m*16+fg*4+r, col j=col0+n*16+fr
  float y2v[4];
  #pragma unroll
  for (int n = 0; n < 4; ++n) y2v[n] = y2[col0 + n * 16 + fr];
  float wm = 0.f;
  float rs[4][4];                    // row sums over this lane's n (static idx only)
  float cs0 = 0.f, cs1 = 0.f, cs2 = 0.f, cs3 = 0.f;  // col sums over this lane's (m,r)
  #pragma unroll
  for (int m = 0; m < 4; ++m) {
    #pragma unroll
    for (int r = 0; r < 4; ++r) {
      float xi = x2[row0 + m * 16 + fg * 4 + r];
      float rsum = 0.f;
      #pragma unroll
      for (int n = 0; n < 4; ++n) {
        float d2 = xi + y2v[n] - 2.0f * acc[m][n][r];
        float w = sqrtf(fmaxf(d2, 0.f));
        wm = fmaxf(wm, w);
        rsum += w;
        if (n == 0) cs0 += w; else if (n == 1) cs1 += w;
        else if (n == 2) cs2 += w; else cs3 += w;
      }
      rs[m][r] = rsum;
    }
  }
  // row sums: reduce across fr (16 lanes of same fg): xor masks 1,2,4,8
  #pragma unroll
  for (int m = 0; m < 4; ++m)
    #pragma unroll
    for (int r = 0; r < 4; ++r) {
      rs[m][r] += __shfl_xor(rs[m][r], 1, 64);
      rs[m][r] += __shfl_xor(rs[m][r], 2, 64);
      rs[m][r] += __shfl_xor(rs[m][r], 4, 64);
      rs[m][r] += __shfl_xor(rs[m][r], 8, 64);
    }
  // col sums: reduce across fg (4 groups): xor masks 16,32
  cs0 += __shfl_xor(cs0, 16, 64); cs0 += __shfl_xor(cs0, 32, 64);
  cs1 += __shfl_xor(cs1, 16, 64); cs1 += __shfl_xor(cs1, 32, 64);
  cs2 += __shfl_xor(cs2, 16, 64); cs2 += __shfl_xor(cs2, 32, 64);
  cs3 += __shfl_xor(cs3, 16, 64); cs3 += __shfl_xor(cs3, 32, 64);
  // max across full wave
  #pragma unroll
  for (int mask = 1; mask < 64; mask <<= 1) wm = fmaxf(wm, __shfl_xor(wm, mask, 64));

  // writer selection (static-index chains; rule #20: no runtime array index)
  // lane fr is the writer for (m,r) = (fr>>2, fr&3); its row lr below is unique per lane
  float rv = rs[0][0];
  #pragma unroll
  for (int m = 0; m < 4; ++m)
    #pragma unroll
    for (int r = 0; r < 4; ++r)
      if (m | r) rv = (fr == m * 4 + r) ? rs[m][r] : rv;
  int lr = rh * 64 + (fr >> 2) * 16 + fg * 4 + (fr & 3);  // local row 0..127
  float cv = (fg == 0) ? cs0 : ((fg == 1) ? cs1 : ((fg == 2) ? cs2 : cs3));
  int lc = ch * 64 + fg * 16 + fr;                        // local col 0..127

  __shared__ float rsum_s[128], csum_s[128], smax[4];
  if (ch == 0) rsum_s[lr] = rv;      // wv 0,2 cover lr 0..63 / 64..127
  if (rh == 0) csum_s[lc] = cv;      // wv 0,1 cover lc 0..63 / 64..127
  if (lane == 0) smax[wv] = wm;
  __syncthreads();
  if (ch == 1) rsum_s[lr] += rv;
  if (rh == 1) csum_s[lc] += cv;
  __syncthreads();
  if (threadIdx.x < 128) {
    Rpart[(size_t)(bi * 128 + threadIdx.x) * 64 + bj] = rsum_s[threadIdx.x];
    Cpart[(size_t)(bj * 128 + threadIdx.x) * 64 + bi] = csum_s[threadIdx.x];
  }
  if (threadIdx.x == 0) {
    float m4 = fmaxf(fmaxf(smax[0], smax[1]), fmaxf(smax[2], smax[3]));
    atomicMax(wmax_bits, __float_as_uint(m4));  // positive floats: uint order == float order
  }
}

// ---- deterministic fixed-order reduction of the 64 tile-partials per row/col ----
__global__ __launch_bounds__(256) void reduce_rc(const float* __restrict__ Rpart,
    const float* __restrict__ Cpart, double* __restrict__ Rd, double* __restrict__ Cd) {
  int t = blockIdx.x * blockDim.x + threadIdx.x;  // 16384 threads
  const float* src = (t < Nn) ? (Rpart + (size_t)t * 64) : (Cpart + (size_t)(t - Nn) * 64);
  double s = 0.0;
  #pragma unroll
  for (int k = 0; k < 64; ++k) s += (double)src[k];
  if (t < Nn) Rd[t] = s; else Cd[t - Nn] = s;
}

__device__ __forceinline__ double bred(double v, double* sb) {
  int tid = threadIdx.x;
  #pragma unroll
  for (int m = 1; m < 64; m <<= 1) v += __shfl_xor(v, m, 64);
  __syncthreads();                   // protect sb reuse across calls
  if ((tid & 63) == 0) sb[tid >> 6] = v;
  __syncthreads();
  double s = (tid < 16) ? sb[tid] : 0.0;
  if (tid < 64) {
    #pragma unroll
    for (int m = 1; m < 16; m <<= 1) s += __shfl_xor(s, m, 16);
  }
  if (tid == 0) sb[0] = s;
  __syncthreads();
  return sb[0];
}

// ---- closed-form Sinkhorn from (R, C, Wmax); exact to fp32 resolution since
// K = 1 - cW with cW <= 7.8e-6: all O((cW)^2) terms are below fp32 ulp.
// Convergence provably fires at it=1 -> final u=u2, v=v2 (ref freeze semantics). ----
__global__ __launch_bounds__(1024) void solve(const double* __restrict__ Rd,
    const double* __restrict__ Cd, const unsigned int* __restrict__ wmax_bits,
    float* __restrict__ out) {
  __shared__ double sb[16];
  int tid = threadIdx.x;
  double wmax = (double)__uint_as_float(*wmax_bits);
  double c = EPS / (128.0 * wmax);
  const double invm = 1.0 / 8192.0;
  double R[8], C[8];
  #pragma unroll
  for (int k = 0; k < 8; ++k) { R[k] = Rd[tid * 8 + k]; C[k] = Cd[tid * 8 + k]; }

  // it=0 u-update: S_v0 = 1 exactly (8192 * 2^-13)
  double part = 0.0;
  #pragma unroll
  for (int k = 0; k < 8; ++k) part += 1.0 / (1.0 - c * invm * R[k]);
  double S_u1 = bred(part, sb);
  // it=0 v-update
  double cu1 = c * (S_u1 * invm);
  part = 0.0;
  #pragma unroll
  for (int k = 0; k < 8; ++k) part += 1.0 / (S_u1 - cu1 * C[k]);
  double S_v1 = bred(part, sb);
  // it=1 u-update (after this, sum|u2-u1| ~ 1e-7 < eps -> done)
  double cv1 = c * (S_v1 * invm);
  double u2[8];
  part = 0.0;
  #pragma unroll
  for (int k = 0; k < 8; ++k) { u2[k] = 1.0 / (S_v1 - cv1 * R[k]); part += u2[k]; }
  double S_u2 = bred(part, sb);
  // it=1 v-update (still applied in the done-iteration, per reference)
  double cu2 = c * (S_u2 * invm);
  part = 0.0;
  #pragma unroll
  for (int k = 0; k < 8; ++k) part += 1.0 / (S_u2 - cu2 * C[k]);
  double S_v2 = bred(part, sb);
  // div = sum_i u2_i * (Kx v2)_i ; (Kx v2)_i = S_v2 - c*mean(v2)*R_i
  double cv2 = c * (S_v2 * invm);
  part = 0.0;
  #pragma unroll
  for (int k = 0; k < 8; ++k) part += u2[k] * (S_v2 - cv2 * R[k]);
  double div = bred(part, sb);
  if (tid == 0) out[0] = (float)(div * invm);  // reduction='mean'
}

extern "C" void kernel_launch(void* const* d_in, const int* in_sizes, int n_in,
                              void* d_out, int out_size, void* d_ws, size_t ws_size,
                              hipStream_t stream) {
  const float* x = (const float*)d_in[0];
  const float* y = (const float*)d_in[1];
  char* ws = (char*)d_ws;
  size_t off = 0;
  unsigned short* xb = (unsigned short*)(ws + off); off += (size_t)Nn * DIM * 2;  // 2 MiB
  unsigned short* yb = (unsigned short*)(ws + off); off += (size_t)Mm * DIM * 2;  // 2 MiB
  float* x2 = (float*)(ws + off); off += (size_t)Nn * 4;
  float* y2 = (float*)(ws + off); off += (size_t)Mm * 4;
  float* Rpart = (float*)(ws + off); off += (size_t)Nn * 64 * 4;                  // 2 MiB
  float* Cpart = (float*)(ws + off); off += (size_t)Mm * 64 * 4;                  // 2 MiB
  double* Rd = (double*)(ws + off); off += (size_t)Nn * 8;
  double* Cd = (double*)(ws + off); off += (size_t)Mm * 8;
  unsigned int* wmax_bits = (unsigned int*)(ws + off); off += 64;
  // total ~8.3 MB

  prep2<<<4096, 256, 0, stream>>>(x, y, xb, yb, x2, y2);
  init_sc<<<1, 1, 0, stream>>>(wmax_bits);
  fused_stats<<<4096, 256, 0, stream>>>(xb, yb, x2, y2, Rpart, Cpart, wmax_bits);
  reduce_rc<<<64, 256, 0, stream>>>(Rpart, Cpart, Rd, Cd);
  solve<<<1, 1024, 0, stream>>>(Rd, Cd, wmax_bits, (float*)d_out);
}

// Round 3
// 92.597 us; speedup vs baseline: 3.1932x; 1.3587x over previous
//
#include <hip/hip_runtime.h>
#include <hip/hip_bf16.h>
#include <math.h>

#define Nn 8192
#define Mm 8192
#define DIM 128
#define EPS 0.001

typedef __attribute__((ext_vector_type(8))) short bf16x8;
typedef __attribute__((ext_vector_type(4))) float f32x4;

// ---- prep: bf16 convert + row squared-norms for BOTH x and y in one launch ----
__global__ __launch_bounds__(256) void prep2(const float* __restrict__ X,
    const float* __restrict__ Y, unsigned short* __restrict__ Xb,
    unsigned short* __restrict__ Yb, float* __restrict__ X2, float* __restrict__ Y2) {
  int gid = blockIdx.x * blockDim.x + threadIdx.x;
  int half = gid >> 19;
  int g = gid & ((1 << 19) - 1);
  int row = g >> 6, lane = g & 63;
  const float* src = half ? Y : X;
  unsigned short* dst = half ? Yb : Xb;
  float* dn = half ? Y2 : X2;
  const float* rp = src + (size_t)row * DIM + lane * 2;
  float a = rp[0], b = rp[1];
  __hip_bfloat16 ha = __float2bfloat16(a), hb = __float2bfloat16(b);
  unsigned short sa = *(unsigned short*)&ha, sb = *(unsigned short*)&hb;
  *(unsigned int*)(dst + (size_t)row * DIM + lane * 2) =
      (unsigned int)sa | ((unsigned int)sb << 16);
  float s = a * a + b * b;
  for (int off = 32; off; off >>= 1) s += __shfl_down(s, off, 64);
  if (lane == 0) dn[row] = s;
}

// ---- fused GEMM + W-statistics; W never stored. No global atomics. ----
__global__ __launch_bounds__(256) void fused_stats(const unsigned short* __restrict__ xb,
    const unsigned short* __restrict__ yb, const float* __restrict__ x2,
    const float* __restrict__ y2, float* __restrict__ Rpart, float* __restrict__ Cpart,
    float* __restrict__ wmaxp) {
  int bid = blockIdx.x;              // 64 x 64 tiles of 128x128
  int bi = bid >> 6, bj = bid & 63;
  int wv = threadIdx.x >> 6, lane = threadIdx.x & 63;
  int rh = wv >> 1, ch = wv & 1;     // row half / col half of this wave's 64x64
  int row0 = bi * 128 + rh * 64;
  int col0 = bj * 128 + ch * 64;
  int fr = lane & 15, fg = lane >> 4;

  f32x4 acc[4][4];
  #pragma unroll
  for (int m = 0; m < 4; ++m)
    #pragma unroll
    for (int n = 0; n < 4; ++n) acc[m][n] = (f32x4){0.f, 0.f, 0.f, 0.f};
  #pragma unroll
  for (int kk = 0; kk < 4; ++kk) {
    int k0 = kk * 32 + fg * 8;
    bf16x8 a[4], b[4];
    #pragma unroll
    for (int m = 0; m < 4; ++m)
      a[m] = *(const bf16x8*)(xb + (size_t)(row0 + m * 16 + fr) * DIM + k0);
    #pragma unroll
    for (int n = 0; n < 4; ++n)
      b[n] = *(const bf16x8*)(yb + (size_t)(col0 + n * 16 + fr) * DIM + k0);
    #pragma unroll
    for (int m = 0; m < 4; ++m)
      #pragma unroll
      for (int n = 0; n < 4; ++n)
        acc[m][n] = __builtin_amdgcn_mfma_f32_16x16x32_bf16(a[m], b[n], acc[m][n], 0, 0, 0);
  }

  // epilogue: w for row i=row0+m*16+fg*4+r, col j=col0+n*16+fr
  float y2v[4];
  #pragma unroll
  for (int n = 0; n < 4; ++n) y2v[n] = y2[col0 + n * 16 + fr];
  float wm = 0.f;
  float rs[4][4];
  float cs0 = 0.f, cs1 = 0.f, cs2 = 0.f, cs3 = 0.f;
  #pragma unroll
  for (int m = 0; m < 4; ++m) {
    #pragma unroll
    for (int r = 0; r < 4; ++r) {
      float xi = x2[row0 + m * 16 + fg * 4 + r];
      float rsum = 0.f;
      #pragma unroll
      for (int n = 0; n < 4; ++n) {
        float d2 = xi + y2v[n] - 2.0f * acc[m][n][r];
        float w = __builtin_amdgcn_sqrtf(fmaxf(d2, 0.f));  // raw v_sqrt_f32, <=2ulp
        wm = fmaxf(wm, w);
        rsum += w;
        if (n == 0) cs0 += w; else if (n == 1) cs1 += w;
        else if (n == 2) cs2 += w; else cs3 += w;
      }
      rs[m][r] = rsum;
    }
  }
  // row sums: reduce across fr (16 lanes sharing fg)
  #pragma unroll
  for (int m = 0; m < 4; ++m)
    #pragma unroll
    for (int r = 0; r < 4; ++r) {
      rs[m][r] += __shfl_xor(rs[m][r], 1, 64);
      rs[m][r] += __shfl_xor(rs[m][r], 2, 64);
      rs[m][r] += __shfl_xor(rs[m][r], 4, 64);
      rs[m][r] += __shfl_xor(rs[m][r], 8, 64);
    }
  // col sums: reduce across fg
  cs0 += __shfl_xor(cs0, 16, 64); cs0 += __shfl_xor(cs0, 32, 64);
  cs1 += __shfl_xor(cs1, 16, 64); cs1 += __shfl_xor(cs1, 32, 64);
  cs2 += __shfl_xor(cs2, 16, 64); cs2 += __shfl_xor(cs2, 32, 64);
  cs3 += __shfl_xor(cs3, 16, 64); cs3 += __shfl_xor(cs3, 32, 64);
  // max across full wave
  #pragma unroll
  for (int mask = 1; mask < 64; mask <<= 1) wm = fmaxf(wm, __shfl_xor(wm, mask, 64));

  // writer selection (static chains only)
  float rv = rs[0][0];
  #pragma unroll
  for (int m = 0; m < 4; ++m)
    #pragma unroll
    for (int r = 0; r < 4; ++r)
      if (m | r) rv = (fr == m * 4 + r) ? rs[m][r] : rv;
  int lr = rh * 64 + (fr >> 2) * 16 + fg * 4 + (fr & 3);  // local row 0..127
  float cv = (fg == 0) ? cs0 : ((fg == 1) ? cs1 : ((fg == 2) ? cs2 : cs3));
  int lc = ch * 64 + fg * 16 + fr;                        // local col 0..127

  __shared__ float rsum_s[128], csum_s[128], smax[4];
  if (ch == 0) rsum_s[lr] = rv;
  if (rh == 0) csum_s[lc] = cv;
  if (lane == 0) smax[wv] = wm;
  __syncthreads();
  if (ch == 1) rsum_s[lr] += rv;
  if (rh == 1) csum_s[lc] += cv;
  __syncthreads();
  // coalesced partial stores: layout [tile_k][8192] on both sides
  if (threadIdx.x < 128) {
    Rpart[(size_t)bj * Nn + bi * 128 + threadIdx.x] = rsum_s[threadIdx.x];
    Cpart[(size_t)bi * Mm + bj * 128 + threadIdx.x] = csum_s[threadIdx.x];
  }
  if (threadIdx.x == 0)
    wmaxp[bid] = fmaxf(fmaxf(smax[0], smax[1]), fmaxf(smax[2], smax[3]));
}

// ---- deterministic fixed-order reduction; coalesced: thread t sums [k][t] ----
__global__ __launch_bounds__(256) void reduce_rc(const float* __restrict__ Rpart,
    const float* __restrict__ Cpart, double* __restrict__ Rd, double* __restrict__ Cd) {
  int t = blockIdx.x * blockDim.x + threadIdx.x;  // 16384 threads
  const float* src = (t < Nn) ? (Rpart + t) : (Cpart + (t - Nn));
  double s = 0.0;
  #pragma unroll
  for (int k = 0; k < 64; ++k) s += (double)src[(size_t)k * Nn];
  if (t < Nn) Rd[t] = s; else Cd[t - Nn] = s;
}

__device__ __forceinline__ double bred(double v, double* sb) {
  int tid = threadIdx.x;
  #pragma unroll
  for (int m = 1; m < 64; m <<= 1) v += __shfl_xor(v, m, 64);
  __syncthreads();
  if ((tid & 63) == 0) sb[tid >> 6] = v;
  __syncthreads();
  double s = (tid < 16) ? sb[tid] : 0.0;
  if (tid < 64) {
    #pragma unroll
    for (int m = 1; m < 16; m <<= 1) s += __shfl_xor(s, m, 16);
  }
  if (tid == 0) sb[0] = s;
  __syncthreads();
  return sb[0];
}

// ---- closed-form Sinkhorn from (R, C, Wmax); exact to fp32 resolution since
// K = 1 - cW with cW <= 7.8e-6. Convergence fires at it=1 (ref freeze). ----
__global__ __launch_bounds__(1024) void solve(const double* __restrict__ Rd,
    const double* __restrict__ Cd, const float* __restrict__ wmaxp,
    float* __restrict__ out) {
  __shared__ double sb[16];
  __shared__ float smx[16];
  int tid = threadIdx.x;
  // wmax = max over 4096 per-block maxima (order-independent)
  float wl = 0.f;
  #pragma unroll
  for (int k = 0; k < 4; ++k) wl = fmaxf(wl, wmaxp[tid * 4 + k]);
  #pragma unroll
  for (int m = 1; m < 64; m <<= 1) wl = fmaxf(wl, __shfl_xor(wl, m, 64));
  if ((tid & 63) == 0) smx[tid >> 6] = wl;
  __syncthreads();
  float wg = (tid < 16) ? smx[tid] : 0.f;
  if (tid < 64) {
    #pragma unroll
    for (int m = 1; m < 16; m <<= 1) wg = fmaxf(wg, __shfl_xor(wg, m, 16));
  }
  if (tid == 0) smx[0] = wg;
  __syncthreads();
  double wmax = (double)smx[0];
  double c = EPS / (128.0 * wmax);
  const double invm = 1.0 / 8192.0;
  double R[8], C[8];
  #pragma unroll
  for (int k = 0; k < 8; ++k) { R[k] = Rd[tid * 8 + k]; C[k] = Cd[tid * 8 + k]; }

  // it=0 u-update: S_v0 = 1 exactly
  double part = 0.0;
  #pragma unroll
  for (int k = 0; k < 8; ++k) part += 1.0 / (1.0 - c * invm * R[k]);
  double S_u1 = bred(part, sb);
  // it=0 v-update
  double cu1 = c * (S_u1 * invm);
  part = 0.0;
  #pragma unroll
  for (int k = 0; k < 8; ++k) part += 1.0 / (S_u1 - cu1 * C[k]);
  double S_v1 = bred(part, sb);
  // it=1 u-update (convergence fires here; v-update below still applies)
  double cv1 = c * (S_v1 * invm);
  double u2[8];
  part = 0.0;
  #pragma unroll
  for (int k = 0; k < 8; ++k) { u2[k] = 1.0 / (S_v1 - cv1 * R[k]); part += u2[k]; }
  double S_u2 = bred(part, sb);
  // it=1 v-update
  double cu2 = c * (S_u2 * invm);
  part = 0.0;
  #pragma unroll
  for (int k = 0; k < 8; ++k) part += 1.0 / (S_u2 - cu2 * C[k]);
  double S_v2 = bred(part, sb);
  // div = sum_i u2_i * (S_v2 - c*mean(v2)*R_i)
  double cv2 = c * (S_v2 * invm);
  part = 0.0;
  #pragma unroll
  for (int k = 0; k < 8; ++k) part += u2[k] * (S_v2 - cv2 * R[k]);
  double div = bred(part, sb);
  if (tid == 0) out[0] = (float)(div * invm);  // reduction='mean'
}

extern "C" void kernel_launch(void* const* d_in, const int* in_sizes, int n_in,
                              void* d_out, int out_size, void* d_ws, size_t ws_size,
                              hipStream_t stream) {
  const float* x = (const float*)d_in[0];
  const float* y = (const float*)d_in[1];
  char* ws = (char*)d_ws;
  size_t off = 0;
  unsigned short* xb = (unsigned short*)(ws + off); off += (size_t)Nn * DIM * 2;
  unsigned short* yb = (unsigned short*)(ws + off); off += (size_t)Mm * DIM * 2;
  float* x2 = (float*)(ws + off); off += (size_t)Nn * 4;
  float* y2 = (float*)(ws + off); off += (size_t)Mm * 4;
  float* Rpart = (float*)(ws + off); off += (size_t)Nn * 64 * 4;
  float* Cpart = (float*)(ws + off); off += (size_t)Mm * 64 * 4;
  double* Rd = (double*)(ws + off); off += (size_t)Nn * 8;
  double* Cd = (double*)(ws + off); off += (size_t)Mm * 8;
  float* wmaxp = (float*)(ws + off); off += 4096 * 4;

  prep2<<<4096, 256, 0, stream>>>(x, y, xb, yb, x2, y2);
  fused_stats<<<4096, 256, 0, stream>>>(xb, yb, x2, y2, Rpart, Cpart, wmaxp);
  reduce_rc<<<64, 256, 0, stream>>>(Rpart, Cpart, Rd, Cd);
  solve<<<1, 1024, 0, stream>>>(Rd, Cd, wmaxp, (float*)d_out);
}